// Round 2
// baseline (143.155 us; speedup 1.0000x reference)
//
#include <hip/hip_runtime.h>
#include <math.h>

// GLIF forward scan. T=64, B=128, N=2048 (derived at runtime from in_sizes).
// All recurrence math in float64: output is 0/1 spikes with threshold 2e-2,
// one flip = fail. f64 error ~1e-16 vs closest spike margin ~1e-7 => safe.
//
// Round-8: D=16 ping-pong prefetch (no register-copy double buffer).
// Rationale: grid gives only 2 waves/SIMD (131072 threads), so latency
// hiding is almost entirely prefetch-depth. D=8 compute phase (~16 f64
// steps ~350cyc) < HBM latency (~900cyc) => stall at each block boundary.
// D=16 ping-pong doubles the issue-to-use distance (~700cyc) and removes
// the 96-VGPR copy per block. fma-collapsed recurrence (r7):
//   y=0: v = dv*v + (I - lt)     y=1: v = dvg*v + (I - ltr)
// with dvg = dv*(1-ga), ltr = lt+rw precomputed. Reassociation error is
// f64-epsilon vs ~1e-7 spike margin: safe (r7 verified absmax=0.0).
// History: r5 1n D=8 ~26us; r6 2n D=8 copy-dbuf (138.4 total);
// r7 fma collapse (139.8 total, noise). Harness fills (256MiB poison,
// ~41us each) dominate the timed window; controllable part is ~30us.

typedef float  fx2 __attribute__((ext_vector_type(2)));
typedef double dx2 __attribute__((ext_vector_type(2)));

__device__ __forceinline__ double dsig(double x) {
    return 1.0 / (1.0 + exp(-x));
}

// Precompute kernel: CH timesteps per thread so sigmoid(beta[n]) (one f64
// exp) amortizes over CH icoef elements. Threads j < N also compute the
// per-n constants.
// ws layout (doubles): [0,N) dv | [N,2N) dvg=dv*(1-ga) | [2N,3N) lt
//                      | [3N,4N) ltr=lt+rw | [4N,5N) thr | [5N, 5N+T*N) icoef
__global__ void glif_pre_kernel(const float* __restrict__ alpha,
                                const float* __restrict__ beta,
                                const float* __restrict__ gamma,
                                const float* __restrict__ tau,
                                const float* __restrict__ Vth,
                                const float* __restrict__ leak,
                                const float* __restrict__ reVth,
                                const float* __restrict__ conduct,
                                double* __restrict__ wsd,
                                int N, int T) {
    constexpr int CH = 4;
    const int nChunks = (T + CH - 1) / CH;
    const int j = blockIdx.x * blockDim.x + threadIdx.x;
    if (j >= N * nChunks) return;
    const int n = j % N;           // consecutive threads -> consecutive n
    const int tc = j / N;
    const int t0 = tc * CH;
    const int tend = (t0 + CH < T) ? (t0 + CH) : T;

    const double be = dsig((double)beta[n]);
    const float* cp = conduct + (size_t)t0 * N + n;
    double* wp = wsd + 5 * N + (size_t)t0 * N + n;
    for (int t = t0; t < tend; ++t) {
        const double cs = dsig((double)*cp);
        *wp = 1.0 - be * (1.0 - cs);   // icoef[t][n]
        cp += N;
        wp += N;
    }

    if (j < N) {
        const int i = j;
        double al     = dsig((double)alpha[i]);
        double ga     = dsig((double)gamma[i]);
        double tau_s  = dsig((double)tau[i]);
        double vth_s  = dsig((double)Vth[i]);
        double leak_s = dsig((double)leak[i]);
        double rev_s  = dsig((double)reVth[i]);
        double dv = 1.0 - al * (1.0 - tau_s);   // decay_v
        double lt = (1.0 - al) * leak_s;        // leak_term
        double rw = (1.0 - ga) * rev_s;         // reset_w
        wsd[0 * N + i] = dv;
        wsd[1 * N + i] = dv * (1.0 - ga);       // dvg (y=1 decay)
        wsd[2 * N + i] = lt;
        wsd[3 * N + i] = lt + rw;               // ltr (y=1 subtract term)
        wsd[4 * N + i] = vth_s;                 // thr
    }
}

// Main scan: 2 neurons/thread, T blocked by D=16 with ping-pong register
// prefetch (no copies; roles alternate each block).
__global__ __launch_bounds__(256) void glif_main2_pp_kernel(
        const float* __restrict__ tx,
        const double* __restrict__ wsd,
        float* __restrict__ out,
        int T, int B, int N) {
    constexpr int D = 16;
    const int half = N >> 1;
    const int idx = blockIdx.x * blockDim.x + threadIdx.x;
    if (idx >= B * half) return;
    const int b = idx / half;
    const int n = (idx - b * half) << 1;

    const double dv0  = wsd[0 * N + n],  dv1  = wsd[0 * N + n + 1];
    const double dvg0 = wsd[1 * N + n],  dvg1 = wsd[1 * N + n + 1];
    const double lt0  = wsd[2 * N + n],  lt1  = wsd[2 * N + n + 1];
    const double ltr0 = wsd[3 * N + n],  ltr1 = wsd[3 * N + n + 1];
    const double th0  = wsd[4 * N + n],  th1  = wsd[4 * N + n + 1];

    const size_t bn = (size_t)b * N + n;
    const size_t stride = (size_t)B * N;   // elements between t-slices (x/out)
    const float*  txp = tx + bn;           // fx2 loads (8-byte aligned: n even)
    const double* icp = wsd + 5 * N + n;   // dx2 loads (16-byte aligned)
    float* op = out + bn;

    double v0 = 0.0, v1 = 0.0;
    bool y0 = false, y1 = false;

    const int nblk = T / D;

    fx2 xa[D], xb[D];
    dx2 ica[D], icb[D];

    const float*  paTx = txp;
    const double* paIc = icp;
    float*        paOut = op;
    const float*  pbTx = txp + (size_t)D * stride;
    const double* pbIc = icp + (size_t)D * N;
    float*        pbOut = op + (size_t)D * stride;
    const size_t  skip   = (size_t)(2 * D) * stride;
    const size_t  skipIc = (size_t)(2 * D) * N;

#define GLIF_LOAD(arr, icarr, ptx, pic)                                        \
    _Pragma("unroll")                                                          \
    for (int j = 0; j < D; ++j) {                                              \
        arr[j]   = __builtin_nontemporal_load(                                 \
                       (const fx2*)(ptx + (size_t)j * stride));                \
        icarr[j] = *(const dx2*)(pic + (size_t)j * N);                         \
    }

#define GLIF_COMPUTE(arr, icarr, pout)                                         \
    _Pragma("unroll")                                                          \
    for (int j = 0; j < D; ++j) {                                              \
        const double I0 = (double)arr[j].x * icarr[j].x;                       \
        const double a0 = y0 ? dvg0 : dv0;                                     \
        const double c0 = y0 ? ltr0 : lt0;                                     \
        v0 = fma(a0, v0, I0 - c0);                                             \
        y0 = v0 > th0;                                                         \
        const double I1 = (double)arr[j].y * icarr[j].y;                       \
        const double a1 = y1 ? dvg1 : dv1;                                     \
        const double c1 = y1 ? ltr1 : lt1;                                     \
        v1 = fma(a1, v1, I1 - c1);                                             \
        y1 = v1 > th1;                                                         \
        fx2 o;                                                                 \
        o.x = y0 ? 1.0f : 0.0f;                                                \
        o.y = y1 ? 1.0f : 0.0f;                                                \
        __builtin_nontemporal_store(o, (fx2*)(pout + (size_t)j * stride));     \
    }

    if (nblk > 0) {
        GLIF_LOAD(xa, ica, paTx, paIc);
    }
    for (int blk = 0; blk < nblk; blk += 2) {
        const bool hasB = (blk + 1) < nblk;
        if (hasB) {
            GLIF_LOAD(xb, icb, pbTx, pbIc);   // in flight across computeA
        }
        GLIF_COMPUTE(xa, ica, paOut);
        paTx += skip; paIc += skipIc; paOut += skip;
        if ((blk + 2) < nblk) {
            GLIF_LOAD(xa, ica, paTx, paIc);   // in flight across computeB
        }
        if (hasB) {
            GLIF_COMPUTE(xb, icb, pbOut);
            pbTx += skip; pbIc += skipIc; pbOut += skip;
        }
    }

#undef GLIF_LOAD
#undef GLIF_COMPUTE

    // Remainder if T % D != 0 (dead for T=64).
    {
        const float*  rtx = tx + bn + (size_t)(nblk * D) * stride;
        const double* ric = wsd + 5 * N + n + (size_t)(nblk * D) * N;
        float*        rop = out + bn + (size_t)(nblk * D) * stride;
        for (int t = nblk * D; t < T; ++t) {
            const fx2 x = *(const fx2*)rtx;
            const dx2 ic = *(const dx2*)ric;
            const double I0 = (double)x.x * ic.x;
            const double a0 = y0 ? dvg0 : dv0;
            const double c0 = y0 ? ltr0 : lt0;
            v0 = fma(a0, v0, I0 - c0);
            y0 = v0 > th0;
            const double I1 = (double)x.y * ic.y;
            const double a1 = y1 ? dvg1 : dv1;
            const double c1 = y1 ? ltr1 : lt1;
            v1 = fma(a1, v1, I1 - c1);
            y1 = v1 > th1;
            fx2 o;
            o.x = y0 ? 1.0f : 0.0f;
            o.y = y1 ? 1.0f : 0.0f;
            *(fx2*)rop = o;
            rtx += stride; ric += N; rop += stride;
        }
    }
}

// Fallback (only if ws too small): computes all sigmoids inline per thread,
// 2 neurons/thread. Same f64 expression tree (fma-collapsed form).
__global__ __launch_bounds__(256) void glif_main_inline_kernel(
        const float* __restrict__ tx,
        const float* __restrict__ alpha,
        const float* __restrict__ beta,
        const float* __restrict__ gamma,
        const float* __restrict__ tau,
        const float* __restrict__ Vth,
        const float* __restrict__ leak,
        const float* __restrict__ reVth,
        const float* __restrict__ conduct,
        float* __restrict__ out,
        int T, int B, int N) {
    const int half = N >> 1;
    const int idx = blockIdx.x * blockDim.x + threadIdx.x;
    if (idx >= B * half) return;
    const int b = idx / half;
    const int n = (idx - b * half) << 1;

    const double al0 = dsig((double)alpha[n]), al1 = dsig((double)alpha[n + 1]);
    const double ga0 = dsig((double)gamma[n]), ga1 = dsig((double)gamma[n + 1]);
    const double be0 = dsig((double)beta[n]),  be1 = dsig((double)beta[n + 1]);
    const double ts0 = dsig((double)tau[n]),   ts1 = dsig((double)tau[n + 1]);
    const double th0 = dsig((double)Vth[n]),   th1 = dsig((double)Vth[n + 1]);
    const double ls0 = dsig((double)leak[n]),  ls1 = dsig((double)leak[n + 1]);
    const double rs0 = dsig((double)reVth[n]), rs1 = dsig((double)reVth[n + 1]);
    const double dv0 = 1.0 - al0 * (1.0 - ts0), dv1 = 1.0 - al1 * (1.0 - ts1);
    const double lt0 = (1.0 - al0) * ls0,       lt1 = (1.0 - al1) * ls1;
    const double rw0 = (1.0 - ga0) * rs0,       rw1 = (1.0 - ga1) * rs1;
    const double dvg0 = dv0 * (1.0 - ga0), dvg1 = dv1 * (1.0 - ga1);
    const double ltr0 = lt0 + rw0,         ltr1 = lt1 + rw1;

    double v0 = 0.0, v1 = 0.0;
    bool y0 = false, y1 = false;

    const size_t bn = (size_t)b * N + n;
    const float* txp = tx + bn;
    float* op = out + bn;
    const float* cp = conduct + n;
    const size_t strideTx = (size_t)B * N;

    for (int t = 0; t < T; ++t) {
        const float2 x = *(const float2*)txp;
        const double ic0 = 1.0 - be0 * (1.0 - dsig((double)cp[0]));
        const double ic1 = 1.0 - be1 * (1.0 - dsig((double)cp[1]));

        const double I0 = (double)x.x * ic0;
        const double a0 = y0 ? dvg0 : dv0;
        const double c0 = y0 ? ltr0 : lt0;
        v0 = fma(a0, v0, I0 - c0);
        y0 = v0 > th0;

        const double I1 = (double)x.y * ic1;
        const double a1 = y1 ? dvg1 : dv1;
        const double c1 = y1 ? ltr1 : lt1;
        v1 = fma(a1, v1, I1 - c1);
        y1 = v1 > th1;

        float2 o;
        o.x = y0 ? 1.0f : 0.0f;
        o.y = y1 ? 1.0f : 0.0f;
        *(float2*)op = o;

        txp += strideTx;
        op += strideTx;
        cp += N;
    }
}

extern "C" void kernel_launch(void* const* d_in, const int* in_sizes, int n_in,
                              void* d_out, int out_size, void* d_ws, size_t ws_size,
                              hipStream_t stream) {
    const float* tx      = (const float*)d_in[0];
    const float* alpha   = (const float*)d_in[1];
    const float* beta    = (const float*)d_in[2];
    const float* gamma   = (const float*)d_in[3];
    const float* tau     = (const float*)d_in[4];
    const float* Vth     = (const float*)d_in[5];
    const float* leak    = (const float*)d_in[6];
    const float* reVth   = (const float*)d_in[7];
    const float* conduct = (const float*)d_in[8];
    float* out = (float*)d_out;

    const int N  = in_sizes[1];        // 2048
    const int TN = in_sizes[8];        // T*N = 131072
    const int T  = TN / N;             // 64
    const int B  = in_sizes[0] / TN;   // 128

    const size_t needed = (size_t)(5 * N + TN) * sizeof(double);
    if (ws_size >= needed && (N & 1) == 0) {
        double* wsd = (double*)d_ws;
        const int nChunks = (T + 3) / 4;
        const int preThreads = N * nChunks;
        const int preBlocks = (preThreads + 255) / 256;
        glif_pre_kernel<<<preBlocks, 256, 0, stream>>>(
            alpha, beta, gamma, tau, Vth, leak, reVth, conduct, wsd, N, T);
        const int total = B * (N >> 1);
        glif_main2_pp_kernel<<<(total + 255) / 256, 256, 0, stream>>>(
            tx, wsd, out, T, B, N);
    } else {
        const int total = B * (N >> 1);
        glif_main_inline_kernel<<<(total + 255) / 256, 256, 0, stream>>>(
            tx, alpha, beta, gamma, tau, Vth, leak, reVth, conduct,
            out, T, B, N);
    }
}

// Round 3
// 139.991 us; speedup vs baseline: 1.0226x; 1.0226x over previous
//
#include <hip/hip_runtime.h>
#include <math.h>

// GLIF forward scan. T=64, B=128, N=2048 (derived at runtime from in_sizes).
// All recurrence math in float64: output is 0/1 spikes with threshold 2e-2,
// one flip = fail. f64 error ~1e-16 vs closest spike margin ~1e-7 => safe.
//
// Round-9: D=8 ping-pong (no register-copy double buffer) + fma-collapsed
// recurrence. r8's D=16 regressed (143.2 vs 138.4): 2 buffers of 16x(fx2+dx2)
// = 192 VGPR data alone -> ~230 total, allocator pressure ate the depth gain.
// D=8 ping-pong keeps the r6-best structure, removes its 96-VGPR copy per
// block, and keeps r7's collapsed chain:
//   y=0: v = dv*v + (I - lt)     y=1: v = dvg*v + (I - ltr)
// (dvg = dv*(1-ga), ltr = lt+rw precomputed; reassociation error ~1e-16
// vs ~1e-7 spike margin; r7/r8 verified absmax=0.0.)
// History: r5 1n D=8 ~26us; r6 2n D=8 copy-dbuf 138.4 total (best);
// r7 fma collapse 139.8; r8 D=16 ping-pong 143.2 (VGPR pressure).
// Timed window is dominated by harness 256MiB ws re-poison fills (~41us
// each, 3 visible); controllable portion (pre+main) ~30us, main HBM floor
// ~20.4us (64MiB tx read + 64MiB out write at 6.3TB/s).

typedef float  fx2 __attribute__((ext_vector_type(2)));
typedef double dx2 __attribute__((ext_vector_type(2)));

__device__ __forceinline__ double dsig(double x) {
    return 1.0 / (1.0 + exp(-x));
}

// Precompute kernel: CH timesteps per thread so sigmoid(beta[n]) (one f64
// exp) amortizes over CH icoef elements. Threads j < N also compute the
// per-n constants.
// ws layout (doubles): [0,N) dv | [N,2N) dvg=dv*(1-ga) | [2N,3N) lt
//                      | [3N,4N) ltr=lt+rw | [4N,5N) thr | [5N, 5N+T*N) icoef
__global__ void glif_pre_kernel(const float* __restrict__ alpha,
                                const float* __restrict__ beta,
                                const float* __restrict__ gamma,
                                const float* __restrict__ tau,
                                const float* __restrict__ Vth,
                                const float* __restrict__ leak,
                                const float* __restrict__ reVth,
                                const float* __restrict__ conduct,
                                double* __restrict__ wsd,
                                int N, int T) {
    constexpr int CH = 4;
    const int nChunks = (T + CH - 1) / CH;
    const int j = blockIdx.x * blockDim.x + threadIdx.x;
    if (j >= N * nChunks) return;
    const int n = j % N;           // consecutive threads -> consecutive n
    const int tc = j / N;
    const int t0 = tc * CH;
    const int tend = (t0 + CH < T) ? (t0 + CH) : T;

    const double be = dsig((double)beta[n]);
    const float* cp = conduct + (size_t)t0 * N + n;
    double* wp = wsd + 5 * N + (size_t)t0 * N + n;
    for (int t = t0; t < tend; ++t) {
        const double cs = dsig((double)*cp);
        *wp = 1.0 - be * (1.0 - cs);   // icoef[t][n]
        cp += N;
        wp += N;
    }

    if (j < N) {
        const int i = j;
        double al     = dsig((double)alpha[i]);
        double ga     = dsig((double)gamma[i]);
        double tau_s  = dsig((double)tau[i]);
        double vth_s  = dsig((double)Vth[i]);
        double leak_s = dsig((double)leak[i]);
        double rev_s  = dsig((double)reVth[i]);
        double dv = 1.0 - al * (1.0 - tau_s);   // decay_v
        double lt = (1.0 - al) * leak_s;        // leak_term
        double rw = (1.0 - ga) * rev_s;         // reset_w
        wsd[0 * N + i] = dv;
        wsd[1 * N + i] = dv * (1.0 - ga);       // dvg (y=1 decay)
        wsd[2 * N + i] = lt;
        wsd[3 * N + i] = lt + rw;               // ltr (y=1 subtract term)
        wsd[4 * N + i] = vth_s;                 // thr
    }
}

// Main scan: 2 neurons/thread, T blocked by D=8 with ping-pong register
// prefetch (no copies; buffer roles alternate each block of the x2 loop).
__global__ __launch_bounds__(256) void glif_main2_pp_kernel(
        const float* __restrict__ tx,
        const double* __restrict__ wsd,
        float* __restrict__ out,
        int T, int B, int N) {
    constexpr int D = 8;
    const int half = N >> 1;
    const int idx = blockIdx.x * blockDim.x + threadIdx.x;
    if (idx >= B * half) return;
    const int b = idx / half;
    const int n = (idx - b * half) << 1;

    const double dv0  = wsd[0 * N + n],  dv1  = wsd[0 * N + n + 1];
    const double dvg0 = wsd[1 * N + n],  dvg1 = wsd[1 * N + n + 1];
    const double lt0  = wsd[2 * N + n],  lt1  = wsd[2 * N + n + 1];
    const double ltr0 = wsd[3 * N + n],  ltr1 = wsd[3 * N + n + 1];
    const double th0  = wsd[4 * N + n],  th1  = wsd[4 * N + n + 1];

    const size_t bn = (size_t)b * N + n;
    const size_t stride = (size_t)B * N;   // elements between t-slices (x/out)
    const float*  txp = tx + bn;           // fx2 loads (8-byte aligned: n even)
    const double* icp = wsd + 5 * N + n;   // dx2 loads (16-byte aligned)
    float* op = out + bn;

    double v0 = 0.0, v1 = 0.0;
    bool y0 = false, y1 = false;

    const int nblk = T / D;

    fx2 xa[D], xb[D];
    dx2 ica[D], icb[D];

    const float*  paTx = txp;
    const double* paIc = icp;
    float*        paOut = op;
    const float*  pbTx = txp + (size_t)D * stride;
    const double* pbIc = icp + (size_t)D * N;
    float*        pbOut = op + (size_t)D * stride;
    const size_t  skip   = (size_t)(2 * D) * stride;
    const size_t  skipIc = (size_t)(2 * D) * N;

#define GLIF_LOAD(arr, icarr, ptx, pic)                                        \
    _Pragma("unroll")                                                          \
    for (int j = 0; j < D; ++j) {                                              \
        arr[j]   = __builtin_nontemporal_load(                                 \
                       (const fx2*)(ptx + (size_t)j * stride));                \
        icarr[j] = *(const dx2*)(pic + (size_t)j * N);                         \
    }

#define GLIF_COMPUTE(arr, icarr, pout)                                         \
    _Pragma("unroll")                                                          \
    for (int j = 0; j < D; ++j) {                                              \
        const double I0 = (double)arr[j].x * icarr[j].x;                       \
        const double a0 = y0 ? dvg0 : dv0;                                     \
        const double c0 = y0 ? ltr0 : lt0;                                     \
        v0 = fma(a0, v0, I0 - c0);                                             \
        y0 = v0 > th0;                                                         \
        const double I1 = (double)arr[j].y * icarr[j].y;                       \
        const double a1 = y1 ? dvg1 : dv1;                                     \
        const double c1 = y1 ? ltr1 : lt1;                                     \
        v1 = fma(a1, v1, I1 - c1);                                             \
        y1 = v1 > th1;                                                         \
        fx2 o;                                                                 \
        o.x = y0 ? 1.0f : 0.0f;                                                \
        o.y = y1 ? 1.0f : 0.0f;                                                \
        __builtin_nontemporal_store(o, (fx2*)(pout + (size_t)j * stride));     \
    }

    if (nblk > 0) {
        GLIF_LOAD(xa, ica, paTx, paIc);
    }
    for (int blk = 0; blk < nblk; blk += 2) {
        const bool hasB = (blk + 1) < nblk;
        if (hasB) {
            GLIF_LOAD(xb, icb, pbTx, pbIc);   // in flight across computeA
        }
        GLIF_COMPUTE(xa, ica, paOut);
        paTx += skip; paIc += skipIc; paOut += skip;
        if ((blk + 2) < nblk) {
            GLIF_LOAD(xa, ica, paTx, paIc);   // in flight across computeB
        }
        if (hasB) {
            GLIF_COMPUTE(xb, icb, pbOut);
            pbTx += skip; pbIc += skipIc; pbOut += skip;
        }
    }

#undef GLIF_LOAD
#undef GLIF_COMPUTE

    // Remainder if T % D != 0 (dead for T=64).
    {
        const float*  rtx = tx + bn + (size_t)(nblk * D) * stride;
        const double* ric = wsd + 5 * N + n + (size_t)(nblk * D) * N;
        float*        rop = out + bn + (size_t)(nblk * D) * stride;
        for (int t = nblk * D; t < T; ++t) {
            const fx2 x = *(const fx2*)rtx;
            const dx2 ic = *(const dx2*)ric;
            const double I0 = (double)x.x * ic.x;
            const double a0 = y0 ? dvg0 : dv0;
            const double c0 = y0 ? ltr0 : lt0;
            v0 = fma(a0, v0, I0 - c0);
            y0 = v0 > th0;
            const double I1 = (double)x.y * ic.y;
            const double a1 = y1 ? dvg1 : dv1;
            const double c1 = y1 ? ltr1 : lt1;
            v1 = fma(a1, v1, I1 - c1);
            y1 = v1 > th1;
            fx2 o;
            o.x = y0 ? 1.0f : 0.0f;
            o.y = y1 ? 1.0f : 0.0f;
            *(fx2*)rop = o;
            rtx += stride; ric += N; rop += stride;
        }
    }
}

// Fallback (only if ws too small): computes all sigmoids inline per thread,
// 2 neurons/thread. Same f64 expression tree (fma-collapsed form).
__global__ __launch_bounds__(256) void glif_main_inline_kernel(
        const float* __restrict__ tx,
        const float* __restrict__ alpha,
        const float* __restrict__ beta,
        const float* __restrict__ gamma,
        const float* __restrict__ tau,
        const float* __restrict__ Vth,
        const float* __restrict__ leak,
        const float* __restrict__ reVth,
        const float* __restrict__ conduct,
        float* __restrict__ out,
        int T, int B, int N) {
    const int half = N >> 1;
    const int idx = blockIdx.x * blockDim.x + threadIdx.x;
    if (idx >= B * half) return;
    const int b = idx / half;
    const int n = (idx - b * half) << 1;

    const double al0 = dsig((double)alpha[n]), al1 = dsig((double)alpha[n + 1]);
    const double ga0 = dsig((double)gamma[n]), ga1 = dsig((double)gamma[n + 1]);
    const double be0 = dsig((double)beta[n]),  be1 = dsig((double)beta[n + 1]);
    const double ts0 = dsig((double)tau[n]),   ts1 = dsig((double)tau[n + 1]);
    const double th0 = dsig((double)Vth[n]),   th1 = dsig((double)Vth[n + 1]);
    const double ls0 = dsig((double)leak[n]),  ls1 = dsig((double)leak[n + 1]);
    const double rs0 = dsig((double)reVth[n]), rs1 = dsig((double)reVth[n + 1]);
    const double dv0 = 1.0 - al0 * (1.0 - ts0), dv1 = 1.0 - al1 * (1.0 - ts1);
    const double lt0 = (1.0 - al0) * ls0,       lt1 = (1.0 - al1) * ls1;
    const double rw0 = (1.0 - ga0) * rs0,       rw1 = (1.0 - ga1) * rs1;
    const double dvg0 = dv0 * (1.0 - ga0), dvg1 = dv1 * (1.0 - ga1);
    const double ltr0 = lt0 + rw0,         ltr1 = lt1 + rw1;

    double v0 = 0.0, v1 = 0.0;
    bool y0 = false, y1 = false;

    const size_t bn = (size_t)b * N + n;
    const float* txp = tx + bn;
    float* op = out + bn;
    const float* cp = conduct + n;
    const size_t strideTx = (size_t)B * N;

    for (int t = 0; t < T; ++t) {
        const float2 x = *(const float2*)txp;
        const double ic0 = 1.0 - be0 * (1.0 - dsig((double)cp[0]));
        const double ic1 = 1.0 - be1 * (1.0 - dsig((double)cp[1]));

        const double I0 = (double)x.x * ic0;
        const double a0 = y0 ? dvg0 : dv0;
        const double c0 = y0 ? ltr0 : lt0;
        v0 = fma(a0, v0, I0 - c0);
        y0 = v0 > th0;

        const double I1 = (double)x.y * ic1;
        const double a1 = y1 ? dvg1 : dv1;
        const double c1 = y1 ? ltr1 : lt1;
        v1 = fma(a1, v1, I1 - c1);
        y1 = v1 > th1;

        float2 o;
        o.x = y0 ? 1.0f : 0.0f;
        o.y = y1 ? 1.0f : 0.0f;
        *(float2*)op = o;

        txp += strideTx;
        op += strideTx;
        cp += N;
    }
}

extern "C" void kernel_launch(void* const* d_in, const int* in_sizes, int n_in,
                              void* d_out, int out_size, void* d_ws, size_t ws_size,
                              hipStream_t stream) {
    const float* tx      = (const float*)d_in[0];
    const float* alpha   = (const float*)d_in[1];
    const float* beta    = (const float*)d_in[2];
    const float* gamma   = (const float*)d_in[3];
    const float* tau     = (const float*)d_in[4];
    const float* Vth     = (const float*)d_in[5];
    const float* leak    = (const float*)d_in[6];
    const float* reVth   = (const float*)d_in[7];
    const float* conduct = (const float*)d_in[8];
    float* out = (float*)d_out;

    const int N  = in_sizes[1];        // 2048
    const int TN = in_sizes[8];        // T*N = 131072
    const int T  = TN / N;             // 64
    const int B  = in_sizes[0] / TN;   // 128

    const size_t needed = (size_t)(5 * N + TN) * sizeof(double);
    if (ws_size >= needed && (N & 1) == 0) {
        double* wsd = (double*)d_ws;
        const int nChunks = (T + 3) / 4;
        const int preThreads = N * nChunks;
        const int preBlocks = (preThreads + 255) / 256;
        glif_pre_kernel<<<preBlocks, 256, 0, stream>>>(
            alpha, beta, gamma, tau, Vth, leak, reVth, conduct, wsd, N, T);
        const int total = B * (N >> 1);
        glif_main2_pp_kernel<<<(total + 255) / 256, 256, 0, stream>>>(
            tx, wsd, out, T, B, N);
    } else {
        const int total = B * (N >> 1);
        glif_main_inline_kernel<<<(total + 255) / 256, 256, 0, stream>>>(
            tx, alpha, beta, gamma, tau, Vth, leak, reVth, conduct,
            out, T, B, N);
    }
}